// Round 7
// baseline (339.799 us; speedup 1.0000x reference)
//
#include <hip/hip_runtime.h>
#include <hip/hip_cooperative_groups.h>

namespace cg = cooperative_groups;

// Problem constants (match reference setup_inputs)
#define B_N 64
#define H_N 512
#define W_N 512
#define T_N 100
#define TB  101        // T+1 buckets (bucket in [0,100])
#define R_N 8
#define NLAB 9         // labels 0..8 (0 = background)
#define NCOL (NLAB * TB)                    // 909 unified hist cols (lab*TB + t), lab0 = bg
#define PIX_PER_IMG (H_N * W_N)

// Cooperative config: 512 blocks = 2 blocks/CU needed; with 14.5 KB LDS the
// runtime's co-residency cap is >=4 blocks/CU even under 64KB-per-CU accounting.
// (R6's 1024-block / 20.6KB version was rejected: cap was 3/CU -> 768 < 1024.)
#define CBLK_PER_IMG 8
#define CGRID (B_N * CBLK_PER_IMG)          // 512
#define CPIX (PIX_PER_IMG / CBLK_PER_IMG)   // 32768
// Fallback (proven R5 path) config
#define FBLK_PER_IMG 32
#define FGRID (B_N * FBLK_PER_IMG)          // 2048
#define FPIX (PIX_PER_IMG / FBLK_PER_IMG)   // 8192

// Exact searchsorted(thr, s, 'right') for thr = np.linspace(0,1,100).astype(f32),
// reproduced bit-exactly in registers: thr[k] = fl32(fl64(k)/99). Guess within +-1;
// branchless correction. (Verified bit-exact: absmax 0 since R4.)
__device__ __forceinline__ int bucket_of(float s) {
    const double C = 1.0 / 99.0;
    int k0 = (int)(s * 99.0f) + 1;                 // s in [0,1) -> k0 in [1,99]
    float tlo = (float)((double)(k0 - 1) * C);     // == thr[k0-1] bit-exact
    float thi = (float)((double)k0 * C);           // == thr[k0]   bit-exact
    return k0 - (s < tlo ? 1 : 0) + (s >= thi ? 1 : 0);
}

// Per-pixel bucket -> per-wave privatized LDS histogram (smem = 4*NCOL ints).
__device__ __forceinline__ void hist_phase(const float* __restrict__ preds,
                                           const int* __restrict__ labels,
                                           int* smem, int tid, int wave,
                                           long base, int pix) {
    const float4* p4 = (const float4*)(preds + base);
    const int4*   l4 = (const int4*)(labels + base);
    int* myh = smem + wave * NCOL;
    const int iters = pix / (256 * 8);
    for (int it = 0; it < iters; ++it) {
        float4 pa = p4[(it * 2 + 0) * 256 + tid];
        float4 pb = p4[(it * 2 + 1) * 256 + tid];
        int4   la = l4[(it * 2 + 0) * 256 + tid];
        int4   lb = l4[(it * 2 + 1) * 256 + tid];
        float ps[8] = {pa.x, pa.y, pa.z, pa.w, pb.x, pb.y, pb.z, pb.w};
        int   ls[8] = {la.x, la.y, la.z, la.w, lb.x, lb.y, lb.z, lb.w};
#pragma unroll
        for (int j = 0; j < 8; ++j)
            atomicAdd(&myh[ls[j] * TB + bucket_of(ps[j])], 1);
    }
}

// Stable rank "argsort" + trapezoid AUC (single block; whole block must call).
__device__ __forceinline__ void rank_sort_auc(int tid, const float* fpr_sh,
                                              const float* ms_sh, int* order,
                                              double* contrib, float* out) {
    if (tid < T_N) {
        float v = fpr_sh[tid];
        int r = 0;
        for (int j = 0; j < T_N; ++j) {
            float u = fpr_sh[j];
            r += (u < v) | ((u == v) & (j < tid));   // stable: ties keep index order
        }
        order[r] = tid;
    }
    __syncthreads();
    if (tid < T_N - 1) {
        int o0 = order[tid], o1 = order[tid + 1];
        double x0 = fpr_sh[o0], x1 = fpr_sh[o1];
        double y0 = ms_sh[o0],  y1 = ms_sh[o1];
        contrib[tid] = (x1 - x0) * (y0 + y1) * 0.5;
    } else if (tid < T_N) {
        contrib[tid] = 0.0;
    }
    __syncthreads();
    if (tid == 0) {
        double s = 0.0;
        for (int i = 0; i < T_N - 1; ++i) s += contrib[i];
        out[0] = (float)s;
    }
}

// ================= single cooperative kernel =================
// LDS budget: exactly 4*NCOL ints = 14544 B; later phases alias it (safe: each
// phase transition crosses a grid.sync / __syncthreads).
__global__ __launch_bounds__(256) void fused_kernel(
    const float* __restrict__ preds, const int* __restrict__ labels,
    int*   __restrict__ rhist,       // (B_N, NCOL)
    float* __restrict__ spro_part,   // (B_N, T_N)
    int*   __restrict__ validc,      // (B_N)
    float* __restrict__ out)
{
    cg::grid_group gg = cg::this_grid();
    __shared__ __align__(16) int smem[4 * NCOL];   // 14544 B, aliased per phase

    const int tid  = threadIdx.x;
    const int bid  = blockIdx.x;
    const int wave = tid >> 6;
    const int gtid = bid * 256 + tid;

    // Phase 0: zero global hist accumulator (512*256 = 131072 threads >= 58176)
    if (gtid < B_N * NCOL) rhist[gtid] = 0;

    for (int i = tid; i < 4 * NCOL; i += 256) smem[i] = 0;
    __syncthreads();

    // Phase A: histogram into per-wave LDS copies
    const int img   = bid / CBLK_PER_IMG;
    const int chunk = bid % CBLK_PER_IMG;
    hist_phase(preds, labels, smem, tid, wave,
               (long)img * PIX_PER_IMG + (long)chunk * CPIX, CPIX);
    __syncthreads();

    gg.sync();   // all zero-writes complete before any flush atomic

    // Phase B: merge wave copies, flush to per-image global hist
    for (int i = tid; i < NCOL; i += 256) {
        int v = smem[i] + smem[NCOL + i] + smem[2 * NCOL + i] + smem[3 * NCOL + i];
        if (v) atomicAdd(&rhist[img * NCOL + i], v);
    }

    gg.sync();   // all flushes complete

    // Phase C: blocks 0..63 -> per-image region sPRO partials (plain stores)
    if (bid < B_N) {
        int*   h_sh    = smem;                       // 909 ints
        float* area_sh = (float*)(smem + 912);       // 8 floats
        for (int i = tid; i < NCOL; i += 256) h_sh[i] = rhist[bid * NCOL + i];
        __syncthreads();
        if (tid < R_N) {
            int a = 0;
            for (int t = 0; t < TB; ++t) a += h_sh[(tid + 1) * TB + t];
            area_sh[tid] = (float)a;
        }
        __syncthreads();
        if (tid < T_N) {
            float s = 0.0f;
#pragma unroll
            for (int r = 0; r < R_N; ++r) {
                int tp = 0;                           // suffix sum over k>t
                for (int k = tid + 1; k < TB; ++k) tp += h_sh[(r + 1) * TB + k];
                float area  = area_sh[r];
                float sat   = fmaxf(area, 1.0f);
                float valid = (area > 0.0f) ? 1.0f : 0.0f;
                s += fminf((float)tp / sat, 1.0f) * valid;
            }
            spro_part[bid * T_N + tid] = s;
        }
        if (tid == 0) {
            int v = 0;
            for (int r = 0; r < R_N; ++r) v += (area_sh[r] > 0.0f) ? 1 : 0;
            validc[bid] = v;
        }
    }

    gg.sync();   // C results visible

    // Phase D: block 0 -> fp/fpr, mean sPRO, stable sort, AUC
    if (bid == 0) {
        int*    bgh     = smem;                      // 101 ints
        float*  ssum_sh = (float*)(smem + 104);      // 100 floats
        float*  fpr_sh  = (float*)(smem + 204);      // 100 floats
        float*  ms_sh   = (float*)(smem + 304);      // 100 floats
        int*    order   = smem + 404;                // 100 ints
        double* contrib = (double*)(smem + 504);     // 100 doubles (offset 2016 B, 8-aligned)
        int*    ndef_sh = smem + 704;

        if (tid < TB)  bgh[tid] = 0;
        if (tid < T_N) ssum_sh[tid] = 0.0f;
        if (tid == 0)  ndef_sh[0] = 0;
        __syncthreads();

        for (int i = tid; i < B_N * TB; i += 256) {
            int b = i / TB, t = i - b * TB;
            atomicAdd(&bgh[t], rhist[b * NCOL + t]);     // lab0 = bg columns
        }
        for (int i = tid; i < B_N * T_N; i += 256)
            atomicAdd(&ssum_sh[i % T_N], spro_part[i]);
        if (tid < B_N) atomicAdd(ndef_sh, validc[tid]);
        __syncthreads();

        if (tid < T_N) {
            int fp_i = 0;                                // #bg with bucket > t
            for (int k = tid + 1; k < TB; ++k) fp_i += bgh[k];
            int tot = fp_i;
            for (int k = 0; k <= tid; ++k) tot += bgh[k];
            float bgt = (float)tot;
            fpr_sh[tid] = (bgt > 0.0f) ? (float)fp_i / fmaxf(bgt, 1.0f) : 0.0f;
            float nd = fmaxf((float)ndef_sh[0], 1.0f);
            ms_sh[tid] = ssum_sh[tid] / nd;
        }
        __syncthreads();

        rank_sort_auc(tid, fpr_sh, ms_sh, order, contrib, out);
    }
}

// ================= fallback: proven R5 3-dispatch path =================
__global__ __launch_bounds__(256) void hist_kernel_fb(
    const float* __restrict__ preds, const int* __restrict__ labels,
    int* __restrict__ rhist)
{
    __shared__ __align__(16) int smem[4 * NCOL];
    const int tid = threadIdx.x, wave = tid >> 6;
    for (int i = tid; i < 4 * NCOL; i += 256) smem[i] = 0;
    __syncthreads();
    const int img   = blockIdx.x / FBLK_PER_IMG;
    const int chunk = blockIdx.x % FBLK_PER_IMG;
    hist_phase(preds, labels, smem, tid, wave,
               (long)img * PIX_PER_IMG + (long)chunk * FPIX, FPIX);
    __syncthreads();
    for (int i = tid; i < NCOL; i += 256) {
        int v = smem[i] + smem[NCOL + i] + smem[2 * NCOL + i] + smem[3 * NCOL + i];
        if (v) atomicAdd(&rhist[img * NCOL + i], v);
    }
}

__global__ __launch_bounds__(256) void post_kernel_fb(
    const int* __restrict__ rhist, float* __restrict__ spro_sum,
    int* __restrict__ n_def, int* __restrict__ done_ctr,
    float* __restrict__ out)
{
    __shared__ int   h_sh[NCOL];
    __shared__ float area_sh[R_N];
    __shared__ int   last_sh;
    const int img = blockIdx.x, tid = threadIdx.x;

    for (int i = tid; i < NCOL; i += 256) h_sh[i] = rhist[img * NCOL + i];
    __syncthreads();
    if (tid < R_N) {
        int a = 0;
        for (int t = 0; t < TB; ++t) a += h_sh[(tid + 1) * TB + t];
        area_sh[tid] = (float)a;
    }
    __syncthreads();
    if (tid < T_N) {
        float s = 0.0f;
#pragma unroll
        for (int r = 0; r < R_N; ++r) {
            int tp = 0;
            for (int k = tid + 1; k < TB; ++k) tp += h_sh[(r + 1) * TB + k];
            float area  = area_sh[r];
            float sat   = fmaxf(area, 1.0f);
            float valid = (area > 0.0f) ? 1.0f : 0.0f;
            s += fminf((float)tp / sat, 1.0f) * valid;
        }
        atomicAdd(&spro_sum[tid], s);
    }
    if (tid == 0) {
        int v = 0;
        for (int r = 0; r < R_N; ++r) v += (area_sh[r] > 0.0f) ? 1 : 0;
        atomicAdd(n_def, v);
    }
    __syncthreads();
    if (tid == 0) {
        int prev = __hip_atomic_fetch_add(done_ctr, 1, __ATOMIC_ACQ_REL,
                                          __HIP_MEMORY_SCOPE_AGENT);
        last_sh = (prev == B_N - 1) ? 1 : 0;
    }
    __syncthreads();
    if (!last_sh) return;

    __shared__ int    bgh[TB];
    __shared__ float  fpr_sh[T_N], ms_sh[T_N];
    __shared__ int    order[T_N];
    __shared__ double contrib[T_N];
    if (tid < TB) bgh[tid] = 0;
    __syncthreads();
    for (int i = tid; i < B_N * TB; i += 256) {
        int b = i / TB, t = i - b * TB;
        atomicAdd(&bgh[t], rhist[b * NCOL + t]);
    }
    __syncthreads();
    if (tid < T_N) {
        int fp_i = 0;
        for (int k = tid + 1; k < TB; ++k) fp_i += bgh[k];
        int tot = fp_i;
        for (int k = 0; k <= tid; ++k) tot += bgh[k];
        float bgt = (float)tot;
        fpr_sh[tid] = (bgt > 0.0f) ? (float)fp_i / fmaxf(bgt, 1.0f) : 0.0f;
        int   ndi = __hip_atomic_load(n_def, __ATOMIC_RELAXED, __HIP_MEMORY_SCOPE_AGENT);
        float ss  = __hip_atomic_load(&spro_sum[tid], __ATOMIC_RELAXED, __HIP_MEMORY_SCOPE_AGENT);
        ms_sh[tid] = ss / fmaxf((float)ndi, 1.0f);
    }
    __syncthreads();
    rank_sort_auc(tid, fpr_sh, ms_sh, order, contrib, out);
}

extern "C" void kernel_launch(void* const* d_in, const int* in_sizes, int n_in,
                              void* d_out, int out_size, void* d_ws, size_t ws_size,
                              hipStream_t stream) {
    const float* preds  = (const float*)d_in[0];
    const int*   labels = (const int*)d_in[2];
    float* out = (float*)d_out;

    int*   rhist     = (int*)d_ws;                       // B*NCOL ints (~233 KB)
    float* spro_sum  = (float*)(rhist + B_N * NCOL);     // T floats   (fallback)
    int*   n_def     = (int*)(spro_sum + T_N);           // 1 int      (fallback)
    int*   done_ctr  = n_def + 1;                        // 1 int      (fallback)
    float* spro_part = (float*)(done_ctr + 1);           // B*T floats (coop)
    int*   validc    = (int*)(spro_part + B_N * T_N);    // B ints     (coop)

    void* args[] = { (void*)&preds, (void*)&labels, (void*)&rhist,
                     (void*)&spro_part, (void*)&validc, (void*)&out };
    hipError_t e = hipLaunchCooperativeKernel((const void*)fused_kernel,
                                              dim3(CGRID), dim3(256), args, 0, stream);
    if (e != hipSuccess) {
        (void)hipGetLastError();   // clear sticky error; run proven split path
        size_t zbytes = sizeof(int) * (size_t)(B_N * NCOL) + sizeof(float) * T_N
                      + 2 * sizeof(int);
        hipMemsetAsync(d_ws, 0, zbytes, stream);
        hist_kernel_fb<<<FGRID, 256, 0, stream>>>(preds, labels, rhist);
        post_kernel_fb<<<B_N, 256, 0, stream>>>(rhist, spro_sum, n_def,
                                                done_ctr, out);
    }
}